// Round 8
// baseline (153.317 us; speedup 1.0000x reference)
//
#include <hip/hip_runtime.h>
#include <hip/hip_fp16.h>

#define EPS 1e-7f
#define CAP 2048      // per-bucket edge window (mean 1024, +32 sigma margin)
#define NBK 784       // max coarse buckets (64 nodes each)

// ---------------------------------------------------------------------------
// K1 (512 thr): blocks [0,binBlocks) bin 8192 edges each into 64-node buckets
// (fixed-capacity windows, LDS-ranked -> ~10-entry contiguous runs).
// Blocks [binBlocks,...) build u32 table tp[n][c] = pack(fp16 ex, fp16 m*ex),
// ex = exp(beta*m), m = relu(x)+eps; row N = zeros (sentinel -> padding
// contributes exactly 0). Packed edge entry: (dst&63)<<16 | src (N < 65536).
// ---------------------------------------------------------------------------
__global__ __launch_bounds__(512)
void binprep_kernel(const int* __restrict__ dst,
                    const int* __restrict__ src, int E, int NB,
                    const float* __restrict__ x,
                    const float* __restrict__ beta, int M,
                    int* __restrict__ ccur,
                    unsigned* __restrict__ packed,
                    unsigned* __restrict__ tp,
                    int binBlocks) {
    if ((int)blockIdx.x < binBlocks) {
        __shared__ int lc[NBK];
        __shared__ int lbase[NBK];
        int tid = threadIdx.x;
        for (int i = tid; i < NB; i += 512) lc[i] = 0;
        __syncthreads();
        int e0 = blockIdx.x * 8192;
        int bb[16], rr[16];
        unsigned pk[16];
        #pragma unroll
        for (int i = 0; i < 16; ++i) {
            int e = e0 + i * 512 + tid;
            bb[i] = 0; rr[i] = 0; pk[i] = 0;
            if (e < E) {
                int d = dst[e];
                bb[i] = d >> 6;
                pk[i] = ((unsigned)(d & 63) << 16) | (unsigned)src[e];
                rr[i] = atomicAdd(&lc[bb[i]], 1);
            }
        }
        __syncthreads();
        for (int i = tid; i < NB; i += 512) {
            int c = lc[i];
            if (c) lbase[i] = i * CAP + atomicAdd(&ccur[i], c);
        }
        __syncthreads();
        #pragma unroll
        for (int i = 0; i < 16; ++i) {
            int e = e0 + i * 512 + tid;
            if (e < E) packed[lbase[bb[i]] + rr[i]] = pk[i];
        }
    } else {
        int blk = blockIdx.x - binBlocks;
        int tid = threadIdx.x;
        const float bt = beta[0];
        #pragma unroll
        for (int p = 0; p < 4; ++p) {
            int i = blk * 8192 + p * 2048 + tid * 4;
            if (i < M) {
                float4 v = *(const float4*)&x[i];
                uint4 o;
                float m, ex;
                m = fmaxf(v.x, 0.f) + EPS; ex = __expf(bt * m);
                o.x = (unsigned)__half_as_ushort(__float2half_rn(ex)) |
                      ((unsigned)__half_as_ushort(__float2half_rn(m * ex)) << 16);
                m = fmaxf(v.y, 0.f) + EPS; ex = __expf(bt * m);
                o.y = (unsigned)__half_as_ushort(__float2half_rn(ex)) |
                      ((unsigned)__half_as_ushort(__float2half_rn(m * ex)) << 16);
                m = fmaxf(v.z, 0.f) + EPS; ex = __expf(bt * m);
                o.z = (unsigned)__half_as_ushort(__float2half_rn(ex)) |
                      ((unsigned)__half_as_ushort(__float2half_rn(m * ex)) << 16);
                m = fmaxf(v.w, 0.f) + EPS; ex = __expf(bt * m);
                o.w = (unsigned)__half_as_ushort(__float2half_rn(ex)) |
                      ((unsigned)__half_as_ushort(__float2half_rn(m * ex)) << 16);
                *(uint4*)&tp[i] = o;
            } else if (i < M + 64) {
                uint4 o; o.x = o.y = o.z = o.w = 0u;
                *(uint4*)&tp[i] = o;
            }
        }
    }
}

// ---------------------------------------------------------------------------
// K2 mega (256 thr, one block per 64-node bucket): LDS hist/scan/scatter of
// the bucket's edge window (CSR fully in LDS, no sorted_src/nse in global),
// quarter-wave-per-node softmax-gather from tp (16 lanes x 16B = full row,
// 4 dwordx4 in flight, no cross-lane reduction), agg in LDS, fused 64x64
// linear epilogue (W^T staged stride-65). Kills 2 dispatches + ~32MB of
// intermediate global traffic.
// ---------------------------------------------------------------------------
__device__ __forceinline__ float f16lo(unsigned w) {
    return __half2float(__ushort_as_half((unsigned short)(w & 0xffffu)));
}
__device__ __forceinline__ float f16hi(unsigned w) {
    return __half2float(__ushort_as_half((unsigned short)(w >> 16)));
}

__global__ __launch_bounds__(256)
void mega_kernel(const unsigned* __restrict__ packed,
                 const int* __restrict__ ccur,
                 const unsigned* __restrict__ tp,
                 const float* __restrict__ W,
                 const float* __restrict__ bias,
                 float* __restrict__ out, int N) {
    __shared__ unsigned stage_pk[CAP];
    __shared__ unsigned short stage16[CAP];
    __shared__ float WtS[64 * 65];     // stride 65 -> 2-way alias = free
    __shared__ float aggS[64][64];
    __shared__ int lc[64];             // per-node counts (stable)
    __shared__ int nstart[64];         // per-node exclusive start
    __shared__ int lcur[64];           // scatter cursor

    const int tid = threadIdx.x;
    const int b = blockIdx.x;

    // stage W transposed
    #pragma unroll
    for (int idx = tid * 4; idx < 64 * 64; idx += 256 * 4) {
        float4 w4 = *(const float4*)&W[idx];
        int j = idx >> 6, c = idx & 63;
        WtS[(c + 0) * 65 + j] = w4.x;
        WtS[(c + 1) * 65 + j] = w4.y;
        WtS[(c + 2) * 65 + j] = w4.z;
        WtS[(c + 3) * 65 + j] = w4.w;
    }
    if (tid < 64) lc[tid] = 0;
    __syncthreads();

    int len = ccur[b];
    if (len > CAP) len = CAP;
    const int rs = b * CAP;
    for (int i = tid; i < len; i += 256) {
        unsigned u = packed[rs + i];
        stage_pk[i] = u;
        atomicAdd(&lc[u >> 16], 1);
    }
    __syncthreads();

    // 64-wide exclusive scan (wave 0)
    if (tid < 64) {
        int v = lc[tid];
        int incl = v;
        #pragma unroll
        for (int d = 1; d < 64; d <<= 1) {
            int t = __shfl_up(incl, d, 64);
            if (tid >= d) incl += t;
        }
        nstart[tid] = incl - v;
        lcur[tid] = incl - v;
    }
    __syncthreads();

    // fine scatter into LDS
    for (int i = tid; i < len; i += 256) {
        unsigned u = stage_pk[i];
        int pos = atomicAdd(&lcur[u >> 16], 1);
        stage16[pos] = (unsigned short)(u & 0xffffu);
    }
    __syncthreads();

    // softmax-gather: quarter-wave per node, 4 sweeps cover 64 nodes
    const int wave = tid >> 6;
    const int lane = tid & 63;
    const int quarter = lane >> 4;
    const int l16 = lane & 15;
    const int qbase = quarter << 4;
    const int chb = l16 << 4;          // byte offset of channel quad
    const int sent = N << 8;           // sentinel row (zeros)
    const unsigned char* tb = (const unsigned char*)tp;

    #pragma unroll
    for (int sweep = 0; sweep < 4; ++sweep) {
        const int ln = sweep * 16 + wave * 4 + quarter;  // 0..63
        const int start = nstart[ln];
        const int cnt = lc[ln];
        float s1x = 0.f, s1y = 0.f, s1z = 0.f, s1w = 0.f;
        float s2x = 0.f, s2y = 0.f, s2z = 0.f, s2w = 0.f;
        for (int chunk = 0; chunk < cnt; chunk += 16) {
            int rem = cnt - chunk;
            if (rem > 16) rem = 16;
            int row = (l16 < rem) ? ((int)stage16[start + chunk + l16] << 8)
                                  : sent;
            for (int k = 0; k < rem; k += 4) {
                int r0 = __shfl(row, qbase + k + 0, 64);
                int r1 = __shfl(row, qbase + k + 1, 64);
                int r2 = __shfl(row, qbase + k + 2, 64);
                int r3 = __shfl(row, qbase + k + 3, 64);
                uint4 u0 = *(const uint4*)(tb + (r0 + chb));
                uint4 u1 = *(const uint4*)(tb + (r1 + chb));
                uint4 u2 = *(const uint4*)(tb + (r2 + chb));
                uint4 u3 = *(const uint4*)(tb + (r3 + chb));
                #define ACC(u) \
                    s1x += f16lo(u.x); s2x += f16hi(u.x); \
                    s1y += f16lo(u.y); s2y += f16hi(u.y); \
                    s1z += f16lo(u.z); s2z += f16hi(u.z); \
                    s1w += f16lo(u.w); s2w += f16hi(u.w)
                ACC(u0); ACC(u1); ACC(u2); ACC(u3);
                #undef ACC
            }
        }
        float4 g;
        g.x = __fdividef(s2x, s1x + 1e-16f);
        g.y = __fdividef(s2y, s1y + 1e-16f);
        g.z = __fdividef(s2z, s1z + 1e-16f);
        g.w = __fdividef(s2w, s1w + 1e-16f);
        *(float4*)&aggS[ln][l16 << 2] = g;
    }
    __syncthreads();

    // fused linear: out[node][lane] = b[lane] + sum_c aggS[ln][c]*W[lane][c]
    const float bv = bias[lane];
    const int nodeBase = b << 6;
    for (int ln = wave; ln < 64; ln += 4) {
        int node = nodeBase + ln;
        if (node >= N) continue;
        float acc = bv;
        #pragma unroll
        for (int c = 0; c < 64; c += 4) {
            float4 a4 = *(const float4*)&aggS[ln][c];  // uniform -> broadcast
            acc = fmaf(a4.x, WtS[(c + 0) * 65 + lane], acc);
            acc = fmaf(a4.y, WtS[(c + 1) * 65 + lane], acc);
            acc = fmaf(a4.z, WtS[(c + 2) * 65 + lane], acc);
            acc = fmaf(a4.w, WtS[(c + 3) * 65 + lane], acc);
        }
        out[((size_t)node << 6) + lane] = acc;
    }
}

// ---------------------------------------------------------------------------
// launch
// ---------------------------------------------------------------------------
extern "C" void kernel_launch(void* const* d_in, const int* in_sizes, int n_in,
                              void* d_out, int out_size, void* d_ws, size_t ws_size,
                              hipStream_t stream) {
    const float* x    = (const float*)d_in[0];
    const int*   ei   = (const int*)d_in[1];    // [2, E]: row0 = dst, row1 = src
    const float* W    = (const float*)d_in[2];
    const float* b    = (const float*)d_in[3];
    const float* beta = (const float*)d_in[4];
    float* out = (float*)d_out;

    const int N = in_sizes[0] / 64;
    const int E = in_sizes[1] / 2;
    const int* dst = ei;
    const int* src = ei + E;
    const int NB = (N + 63) >> 6;               // 782 buckets of 64 nodes
    const int M = N * 64;

    auto align = [](size_t v) { return (v + 255) & ~(size_t)255; };
    size_t off = 0;
    char* ws = (char*)d_ws;
    int* ccur = (int*)(ws + off);         off += align((size_t)NB * 4);
    unsigned* packed = (unsigned*)(ws + off);
    off += align((size_t)NB * CAP * 4);
    unsigned* tp = (unsigned*)(ws + off); off += align(((size_t)N + 1) * 64 * 4);

    const int binBlocks  = (E + 8191) / 8192;        // 98
    const int prepBlocks = (M + 64 + 8191) / 8192;   // 391
    hipMemsetAsync(ccur, 0, (size_t)NB * 4, stream);
    binprep_kernel<<<binBlocks + prepBlocks, 512, 0, stream>>>(
        dst, src, E, NB, x, beta, M, ccur, packed, tp, binBlocks);
    mega_kernel<<<NB, 256, 0, stream>>>(packed, ccur, tp, W, b, out, N);
}

// Round 9
// 139.321 us; speedup vs baseline: 1.1005x; 1.1005x over previous
//
#include <hip/hip_runtime.h>
#include <hip/hip_fp16.h>

#define EPS 1e-7f

typedef _Float16 half8 __attribute__((ext_vector_type(8)));
typedef float f32x4 __attribute__((ext_vector_type(4)));

// ---------------------------------------------------------------------------
// K1 (512 thr): blocks [0,binBlocks) bin 2048 edges each into 256-node coarse
// buckets (fixed-capacity windows, LDS-ranked -> contiguous runs). Blocks
// [binBlocks,...) build fp16 table tm[n][c] = relu(x)+eps (2B/ch, 128B rows),
// sentinel row N = -32 (exp2(1.44*beta*-32) ~ 1e-14 -> padding contributes 0),
// and block binBlocks also converts W to fp16 row-major (for MFMA linear).
// Packed edge entry: (dst&255)<<16 | src  (needs N < 65536).
// ---------------------------------------------------------------------------
__global__ __launch_bounds__(512)
void binprep_kernel(const int* __restrict__ dst,
                    const int* __restrict__ src, int E, int cap,
                    const float* __restrict__ x,
                    const float* __restrict__ W, int M,
                    int* __restrict__ ccur,
                    unsigned* __restrict__ packed,
                    unsigned short* __restrict__ tm,
                    unsigned short* __restrict__ Wh,
                    int binBlocks) {
    if ((int)blockIdx.x < binBlocks) {
        __shared__ int lc[256];
        __shared__ int lbase[256];
        int tid = threadIdx.x;
        if (tid < 256) lc[tid] = 0;
        __syncthreads();
        int e0 = blockIdx.x * 2048;
        int bb[4], rr[4];
        unsigned pk[4];
        #pragma unroll
        for (int i = 0; i < 4; ++i) {
            int e = e0 + i * 512 + tid;
            bb[i] = 0; rr[i] = 0; pk[i] = 0;
            if (e < E) {
                int d = dst[e];
                bb[i] = d >> 8;
                pk[i] = ((unsigned)(d & 255) << 16) | (unsigned)src[e];
                rr[i] = atomicAdd(&lc[bb[i]], 1);
            }
        }
        __syncthreads();
        if (tid < 256) {
            int c = lc[tid];
            if (c) lbase[tid] = tid * cap + atomicAdd(&ccur[tid], c);
        }
        __syncthreads();
        #pragma unroll
        for (int i = 0; i < 4; ++i) {
            int e = e0 + i * 512 + tid;
            if (e < E) packed[lbase[bb[i]] + rr[i]] = pk[i];
        }
    } else {
        int blk = blockIdx.x - binBlocks;
        int tid = threadIdx.x;
        if (blk == 0) {  // convert W (64x64) to fp16 row-major
            #pragma unroll
            for (int j = 0; j < 8; ++j) {
                int i = tid * 8 + j;
                Wh[i] = __half_as_ushort(__float2half_rn(W[i]));
            }
        }
        const unsigned short sent = __half_as_ushort(__float2half_rn(-32.f));
        #pragma unroll
        for (int p = 0; p < 4; ++p) {
            int i = blk * 8192 + p * 2048 + tid * 4;
            if (i < M) {
                float4 v = *(const float4*)&x[i];
                ushort4 o;
                o.x = __half_as_ushort(__float2half_rn(fmaxf(v.x, 0.f) + EPS));
                o.y = __half_as_ushort(__float2half_rn(fmaxf(v.y, 0.f) + EPS));
                o.z = __half_as_ushort(__float2half_rn(fmaxf(v.z, 0.f) + EPS));
                o.w = __half_as_ushort(__float2half_rn(fmaxf(v.w, 0.f) + EPS));
                *(ushort4*)&tm[i] = o;
            } else if (i < M + 64) {
                ushort4 o; o.x = o.y = o.z = o.w = sent;
                *(ushort4*)&tm[i] = o;
            }
        }
    }
}

// ---------------------------------------------------------------------------
// K2 (512 thr): one block per 256-node bucket. Stage packed window in LDS;
// in-LDS hist of dst-low-byte -> 256-wide scan -> per-node (start,end) int2 +
// LDS fine scatter, then coalesced u32-pair write of u16 sorted_src.
// ---------------------------------------------------------------------------
__global__ __launch_bounds__(512)
void fine_kernel(const unsigned* __restrict__ packed,
                 const int* __restrict__ ccur, int cap,
                 int2* __restrict__ nse,
                 unsigned short* __restrict__ sorted_src, int N) {
    __shared__ int lc[256];
    __shared__ int lcur[256];
    __shared__ int wsum[4];
    __shared__ unsigned stage_pk[6656];
    __shared__ unsigned short stage16[6656];
    int tid = threadIdx.x, b = blockIdx.x;
    int rs = b * cap;
    int len = ccur[b];
    if (tid < 256) lc[tid] = 0;
    __syncthreads();
    for (int i = tid; i < len; i += 512) {
        unsigned u = packed[rs + i];
        stage_pk[i] = u;
        atomicAdd(&lc[u >> 16], 1);
    }
    __syncthreads();
    if (tid < 256) {
        int lane = tid & 63, wid = tid >> 6;
        int incl = lc[tid];
        #pragma unroll
        for (int d = 1; d < 64; d <<= 1) {
            int t = __shfl_up(incl, d, 64);
            if (lane >= d) incl += t;
        }
        lcur[tid] = incl;
        if (lane == 63) wsum[wid] = incl;
    }
    __syncthreads();
    if (tid < 256) {
        int wid = tid >> 6;
        int base = 0;
        for (int w = 0; w < wid; ++w) base += wsum[w];
        int v = lc[tid];
        int excl = base + lcur[tid] - v;
        lcur[tid] = excl;
        int node = b * 256 + tid;
        if (node < N) nse[node] = make_int2(rs + excl, rs + excl + v);
    }
    __syncthreads();
    for (int i = tid; i < len; i += 512) {
        unsigned u = stage_pk[i];
        int pos = atomicAdd(&lcur[u >> 16], 1);
        stage16[pos] = (unsigned short)(u & 0xffffu);
    }
    __syncthreads();
    unsigned* dst32 = (unsigned*)&sorted_src[rs];
    int len2 = (len + 1) >> 1;
    for (int i = tid; i < len2; i += 512) {
        unsigned lo = stage16[2 * i];
        unsigned hi = (2 * i + 1 < len) ? (unsigned)stage16[2 * i + 1] : 0u;
        dst32[i] = lo | (hi << 16);
    }
}

// ---------------------------------------------------------------------------
// K3 gather (256 thr, no LDS): quarter-wave per node; 16 lanes x 8B = one
// full 128B fp16 row; lane owns 4 channels. Fixed 16-edge chunks (sentinel-
// padded -> statically unrolled, 16 loads in flight). exp via exp2f(m*c),
// c = beta*log2(e). Writes agg as fp16 (uint2/lane) for the MFMA linear.
// ---------------------------------------------------------------------------
__device__ __forceinline__ float hlo(unsigned w) {
    return __half2float(__ushort_as_half((unsigned short)(w & 0xffffu)));
}
__device__ __forceinline__ float hhi(unsigned w) {
    return __half2float(__ushort_as_half((unsigned short)(w >> 16)));
}

__global__ __launch_bounds__(256)
void gather_kernel(const unsigned short* __restrict__ tm,
                   const int2* __restrict__ nse,
                   const unsigned short* __restrict__ ss,
                   const float* __restrict__ beta,
                   unsigned short* __restrict__ agg16, int N) {
    const int tid = threadIdx.x;
    const int lane = tid & 63;
    const int quarter = lane >> 4;
    const int l16 = lane & 15;
    const int qbase = quarter << 4;
    const int chb = l16 << 3;            // byte offset of 4-channel group
    const int sent = N << 7;             // sentinel row byte offset
    const unsigned char* tb = (const unsigned char*)tm;
    const float c = beta[0] * 1.4426950408889634f;

    const int node = blockIdx.x * 16 + (tid >> 6) * 4 + quarter;
    int start = 0, cnt = 0;
    if (node < N) { int2 se = nse[node]; start = se.x; cnt = se.y - se.x; }

    float s1x = 0.f, s1y = 0.f, s1z = 0.f, s1w = 0.f;
    float s2x = 0.f, s2y = 0.f, s2z = 0.f, s2w = 0.f;

    for (int chunk = 0; chunk < cnt; chunk += 16) {
        int rem = cnt - chunk;
        if (rem > 16) rem = 16;
        int row = (l16 < rem) ? ((int)ss[start + chunk + l16] << 7) : sent;
        #pragma unroll
        for (int k = 0; k < 16; k += 4) {
            int r0 = __shfl(row, qbase + k + 0, 64);
            int r1 = __shfl(row, qbase + k + 1, 64);
            int r2 = __shfl(row, qbase + k + 2, 64);
            int r3 = __shfl(row, qbase + k + 3, 64);
            uint2 u0 = *(const uint2*)(tb + (r0 + chb));
            uint2 u1 = *(const uint2*)(tb + (r1 + chb));
            uint2 u2 = *(const uint2*)(tb + (r2 + chb));
            uint2 u3 = *(const uint2*)(tb + (r3 + chb));
            #define ACC(u) { \
                float m0 = hlo(u.x), m1 = hhi(u.x); \
                float m2 = hlo(u.y), m3 = hhi(u.y); \
                float e0 = exp2f(m0 * c), e1 = exp2f(m1 * c); \
                float e2 = exp2f(m2 * c), e3 = exp2f(m3 * c); \
                s1x += e0; s2x = fmaf(m0, e0, s2x); \
                s1y += e1; s2y = fmaf(m1, e1, s2y); \
                s1z += e2; s2z = fmaf(m2, e2, s2z); \
                s1w += e3; s2w = fmaf(m3, e3, s2w); }
            ACC(u0); ACC(u1); ACC(u2); ACC(u3);
            #undef ACC
        }
    }
    if (node < N) {
        float gx = __fdividef(s2x, s1x + 1e-16f);
        float gy = __fdividef(s2y, s1y + 1e-16f);
        float gz = __fdividef(s2z, s1z + 1e-16f);
        float gw = __fdividef(s2w, s1w + 1e-16f);
        uint2 o;
        o.x = (unsigned)__half_as_ushort(__float2half_rn(gx)) |
              ((unsigned)__half_as_ushort(__float2half_rn(gy)) << 16);
        o.y = (unsigned)__half_as_ushort(__float2half_rn(gz)) |
              ((unsigned)__half_as_ushort(__float2half_rn(gw)) << 16);
        *(uint2*)((unsigned char*)agg16 + ((size_t)node << 7) + chb) = o;
    }
}

// ---------------------------------------------------------------------------
// K4 linear via MFMA: out = agg @ W^T + b. One wave per 16 nodes; 4 tiles of
// 16 out-ch; K=64 as two mfma_f32_16x16x32_f16. A[m=lane&15][k=(lane>>4)*8+j]
// from agg16; B[k][n=lane&15] = W[n][k] from Wh rows. C/D: col=lane&15,
// row=(lane>>4)*4+reg (m89-verified layout).
// ---------------------------------------------------------------------------
__global__ __launch_bounds__(256)
void linear_kernel(const unsigned short* __restrict__ agg16,
                   const unsigned short* __restrict__ Wh,
                   const float* __restrict__ b,
                   float* __restrict__ out, int N, int G) {
    const int tid = threadIdx.x;
    const int wave = tid >> 6;
    const int lane = tid & 63;
    const int l16 = lane & 15;
    const int quad = lane >> 4;
    const int g = blockIdx.x * 4 + wave;
    if (g >= G) return;

    const unsigned char* ab = (const unsigned char*)agg16;
    const unsigned char* wb = (const unsigned char*)Wh;

    // A fragments: node row = g*16 + l16, k-halves at byte h*64 + quad*16
    half8 a0 = *(const half8*)(ab + (((size_t)(g * 16 + l16)) << 7) + quad * 16);
    half8 a1 = *(const half8*)(ab + (((size_t)(g * 16 + l16)) << 7) + 64 + quad * 16);

    f32x4 acc[4];
    float bias[4];
    #pragma unroll
    for (int t = 0; t < 4; ++t) {
        // B fragment: lane's out-ch n = 16t + l16 -> Wh row n, 8 halves at
        // byte offset row*128 + h*64 + quad*16
        const unsigned char* wr = wb + (((size_t)(16 * t + l16)) << 7) + quad * 16;
        half8 b0 = *(const half8*)(wr);
        half8 b1 = *(const half8*)(wr + 64);
        acc[t] = (f32x4){0.f, 0.f, 0.f, 0.f};
        acc[t] = __builtin_amdgcn_mfma_f32_16x16x32_f16(a0, b0, acc[t], 0, 0, 0);
        acc[t] = __builtin_amdgcn_mfma_f32_16x16x32_f16(a1, b1, acc[t], 0, 0, 0);
        bias[t] = b[16 * t + l16];
    }
    #pragma unroll
    for (int t = 0; t < 4; ++t) {
        #pragma unroll
        for (int r = 0; r < 4; ++r) {
            int node = g * 16 + quad * 4 + r;
            if (node < N)
                out[((size_t)node << 6) + 16 * t + l16] = acc[t][r] + bias[t];
        }
    }
}

// ---------------------------------------------------------------------------
// launch
// ---------------------------------------------------------------------------
extern "C" void kernel_launch(void* const* d_in, const int* in_sizes, int n_in,
                              void* d_out, int out_size, void* d_ws, size_t ws_size,
                              hipStream_t stream) {
    const float* x    = (const float*)d_in[0];
    const int*   ei   = (const int*)d_in[1];    // [2, E]: row0 = dst, row1 = src
    const float* W    = (const float*)d_in[2];
    const float* b    = (const float*)d_in[3];
    const float* beta = (const float*)d_in[4];
    float* out = (float*)d_out;

    const int N = in_sizes[0] / 64;
    const int E = in_sizes[1] / 2;
    const int* dst = ei;
    const int* src = ei + E;
    const int NB = (N + 255) >> 8;              // 196 coarse buckets
    const int M = N * 64;
    const int G = (N + 15) / 16;                // 16-node groups

    int cap = (E + NB - 1) / NB;
    cap = ((cap + cap / 2 + 256) + 255) & ~255;
    if (cap > 6656) cap = 6656;

    auto align = [](size_t v) { return (v + 255) & ~(size_t)255; };
    size_t off = 0;
    char* ws = (char*)d_ws;
    int2* nse = (int2*)(ws + off);        off += align((size_t)N * 8);
    int* ccur = (int*)(ws + off);         off += align((size_t)NB * 4);
    unsigned* packed = (unsigned*)(ws + off);
    off += align((size_t)NB * cap * 4);
    unsigned short* sorted_src = (unsigned short*)(ws + off);
    off += align((size_t)NB * cap * 2);
    unsigned short* tm = (unsigned short*)(ws + off);   // (N+1)*64 fp16
    off += align(((size_t)N + 1) * 64 * 2);
    unsigned short* agg16 = (unsigned short*)(ws + off); // G*16*64 fp16
    off += align((size_t)G * 16 * 64 * 2);
    unsigned short* Wh = (unsigned short*)(ws + off);    // 64*64 fp16
    off += align(64 * 64 * 2);

    const int binBlocks  = (E + 2047) / 2048;
    const int prepBlocks = (M + 64 + 8191) / 8192;
    hipMemsetAsync(ccur, 0, (size_t)NB * 4, stream);
    binprep_kernel<<<binBlocks + prepBlocks, 512, 0, stream>>>(
        dst, src, E, cap, x, W, M, ccur, packed, tm, Wh, binBlocks);
    fine_kernel<<<NB, 512, 0, stream>>>(packed, ccur, cap, nse, sorted_src, N);
    gather_kernel<<<G, 256, 0, stream>>>(tm, nse, sorted_src, beta, agg16, N);
    linear_kernel<<<(G + 3) / 4, 256, 0, stream>>>(agg16, Wh, b, out, N, G);
}

// Round 10
// 130.172 us; speedup vs baseline: 1.1778x; 1.0703x over previous
//
#include <hip/hip_runtime.h>
#include <hip/hip_fp16.h>

#define EPS 1e-7f

typedef _Float16 half8 __attribute__((ext_vector_type(8)));
typedef float f32x4 __attribute__((ext_vector_type(4)));

// ---------------------------------------------------------------------------
// K1 (512 thr): blocks [0,binBlocks) bin 2048 edges each into 256-node coarse
// buckets (fixed-capacity windows, LDS-ranked -> contiguous runs). Blocks
// [binBlocks,...) build u32 pair-table tp[n][c] = (fp16 ex | fp16 m*ex << 16),
// ex = exp(beta*m), m = relu(x)+eps; row N = zeros (sentinel: fp16 +0 adds
// are exact -> padding contributes nothing). Block binBlocks also converts
// W to fp16 row-major for the MFMA linear.
// Packed edge entry: (dst&255)<<16 | src  (needs N < 65536).
// ---------------------------------------------------------------------------
__global__ __launch_bounds__(512)
void binprep_kernel(const int* __restrict__ dst,
                    const int* __restrict__ src, int E, int cap,
                    const float* __restrict__ x,
                    const float* __restrict__ W,
                    const float* __restrict__ beta, int M,
                    int* __restrict__ ccur,
                    unsigned* __restrict__ packed,
                    unsigned* __restrict__ tp,
                    unsigned short* __restrict__ Wh,
                    int binBlocks) {
    if ((int)blockIdx.x < binBlocks) {
        __shared__ int lc[256];
        __shared__ int lbase[256];
        int tid = threadIdx.x;
        if (tid < 256) lc[tid] = 0;
        __syncthreads();
        int e0 = blockIdx.x * 2048;
        int bb[4], rr[4];
        unsigned pk[4];
        #pragma unroll
        for (int i = 0; i < 4; ++i) {
            int e = e0 + i * 512 + tid;
            bb[i] = 0; rr[i] = 0; pk[i] = 0;
            if (e < E) {
                int d = dst[e];
                bb[i] = d >> 8;
                pk[i] = ((unsigned)(d & 255) << 16) | (unsigned)src[e];
                rr[i] = atomicAdd(&lc[bb[i]], 1);
            }
        }
        __syncthreads();
        if (tid < 256) {
            int c = lc[tid];
            if (c) lbase[tid] = tid * cap + atomicAdd(&ccur[tid], c);
        }
        __syncthreads();
        #pragma unroll
        for (int i = 0; i < 4; ++i) {
            int e = e0 + i * 512 + tid;
            if (e < E) packed[lbase[bb[i]] + rr[i]] = pk[i];
        }
    } else {
        int blk = blockIdx.x - binBlocks;
        int tid = threadIdx.x;
        if (blk == 0) {  // convert W (64x64) to fp16 row-major
            #pragma unroll
            for (int j = 0; j < 8; ++j) {
                int i = tid * 8 + j;
                Wh[i] = __half_as_ushort(__float2half_rn(W[i]));
            }
        }
        const float bt = beta[0];
        #pragma unroll
        for (int p = 0; p < 4; ++p) {
            int i = blk * 8192 + p * 2048 + tid * 4;
            if (i < M) {
                float4 v = *(const float4*)&x[i];
                uint4 o;
                float m, ex;
                m = fmaxf(v.x, 0.f) + EPS; ex = __expf(bt * m);
                o.x = (unsigned)__half_as_ushort(__float2half_rn(ex)) |
                      ((unsigned)__half_as_ushort(__float2half_rn(m * ex)) << 16);
                m = fmaxf(v.y, 0.f) + EPS; ex = __expf(bt * m);
                o.y = (unsigned)__half_as_ushort(__float2half_rn(ex)) |
                      ((unsigned)__half_as_ushort(__float2half_rn(m * ex)) << 16);
                m = fmaxf(v.z, 0.f) + EPS; ex = __expf(bt * m);
                o.z = (unsigned)__half_as_ushort(__float2half_rn(ex)) |
                      ((unsigned)__half_as_ushort(__float2half_rn(m * ex)) << 16);
                m = fmaxf(v.w, 0.f) + EPS; ex = __expf(bt * m);
                o.w = (unsigned)__half_as_ushort(__float2half_rn(ex)) |
                      ((unsigned)__half_as_ushort(__float2half_rn(m * ex)) << 16);
                *(uint4*)&tp[i] = o;
            } else if (i < M + 64) {
                uint4 o; o.x = o.y = o.z = o.w = 0u;
                *(uint4*)&tp[i] = o;
            }
        }
    }
}

// ---------------------------------------------------------------------------
// K2 (512 thr): one block per 256-node bucket. Stage packed window in LDS;
// in-LDS hist of dst-low-byte -> 256-wide scan -> per-node (start,end) int2 +
// LDS fine scatter, then coalesced u32-pair write of u16 sorted_src.
// ---------------------------------------------------------------------------
__global__ __launch_bounds__(512)
void fine_kernel(const unsigned* __restrict__ packed,
                 const int* __restrict__ ccur, int cap,
                 int2* __restrict__ nse,
                 unsigned short* __restrict__ sorted_src, int N) {
    __shared__ int lc[256];
    __shared__ int lcur[256];
    __shared__ int wsum[4];
    __shared__ unsigned stage_pk[6656];
    __shared__ unsigned short stage16[6656];
    int tid = threadIdx.x, b = blockIdx.x;
    int rs = b * cap;
    int len = ccur[b];
    if (tid < 256) lc[tid] = 0;
    __syncthreads();
    for (int i = tid; i < len; i += 512) {
        unsigned u = packed[rs + i];
        stage_pk[i] = u;
        atomicAdd(&lc[u >> 16], 1);
    }
    __syncthreads();
    if (tid < 256) {
        int lane = tid & 63, wid = tid >> 6;
        int incl = lc[tid];
        #pragma unroll
        for (int d = 1; d < 64; d <<= 1) {
            int t = __shfl_up(incl, d, 64);
            if (lane >= d) incl += t;
        }
        lcur[tid] = incl;
        if (lane == 63) wsum[wid] = incl;
    }
    __syncthreads();
    if (tid < 256) {
        int wid = tid >> 6;
        int base = 0;
        for (int w = 0; w < wid; ++w) base += wsum[w];
        int v = lc[tid];
        int excl = base + lcur[tid] - v;
        lcur[tid] = excl;
        int node = b * 256 + tid;
        if (node < N) nse[node] = make_int2(rs + excl, rs + excl + v);
    }
    __syncthreads();
    for (int i = tid; i < len; i += 512) {
        unsigned u = stage_pk[i];
        int pos = atomicAdd(&lcur[u >> 16], 1);
        stage16[pos] = (unsigned short)(u & 0xffffu);
    }
    __syncthreads();
    unsigned* dst32 = (unsigned*)&sorted_src[rs];
    int len2 = (len + 1) >> 1;
    for (int i = tid; i < len2; i += 512) {
        unsigned lo = stage16[2 * i];
        unsigned hi = (2 * i + 1 < len) ? (unsigned)stage16[2 * i + 1] : 0u;
        dst32[i] = lo | (hi << 16);
    }
}

// ---------------------------------------------------------------------------
// K3 gather (256 thr, no LDS): quarter-wave per node; 16 lanes x 16B = one
// full 256B pair-row; lane owns 4 channels. Inner loop is load + v_pk_add_f16
// ONLY (s1 in lo half, s2 in hi half of each packed accumulator) — no exp,
// no cvt, no fma in the E*64-scale loop. Two accumulator banks (<=8 fp16
// adds each) flushed to f32 once per 16-edge chunk bound rounding to ~0.2%.
// Sentinel row (zeros) absorbs padding exactly. Writes agg as fp16 rows.
// ---------------------------------------------------------------------------
__global__ __launch_bounds__(256)
void gather_kernel(const unsigned* __restrict__ tp,
                   const int2* __restrict__ nse,
                   const unsigned short* __restrict__ ss,
                   unsigned short* __restrict__ agg16, int N) {
    const int tid = threadIdx.x;
    const int lane = tid & 63;
    const int quarter = lane >> 4;
    const int l16 = lane & 15;
    const int qbase = quarter << 4;
    const int chb = l16 << 4;            // byte offset of 4-channel pair group
    const int sent = N << 8;             // sentinel row byte offset (zeros)
    const unsigned char* tb = (const unsigned char*)tp;

    const int node = blockIdx.x * 16 + (tid >> 6) * 4 + quarter;
    int start = 0, cnt = 0;
    if (node < N) { int2 se = nse[node]; start = se.x; cnt = se.y - se.x; }

    float2 fs0 = {0.f, 0.f}, fs1 = {0.f, 0.f};
    float2 fs2 = {0.f, 0.f}, fs3 = {0.f, 0.f};

    for (int chunk = 0; chunk < cnt; chunk += 16) {
        int rem = cnt - chunk;
        if (rem > 16) rem = 16;
        int row = (l16 < rem) ? ((int)ss[start + chunk + l16] << 8) : sent;
        __half2 a0 = __half2{__ushort_as_half(0), __ushort_as_half(0)};
        __half2 a1 = a0, a2 = a0, a3 = a0;
        __half2 b0 = a0, b1 = a0, b2 = a0, b3 = a0;
        #pragma unroll
        for (int k = 0; k < 16; k += 4) {
            int r0 = __shfl(row, qbase + k + 0, 64);
            int r1 = __shfl(row, qbase + k + 1, 64);
            int r2 = __shfl(row, qbase + k + 2, 64);
            int r3 = __shfl(row, qbase + k + 3, 64);
            uint4 u0 = *(const uint4*)(tb + (r0 + chb));
            uint4 u1 = *(const uint4*)(tb + (r1 + chb));
            uint4 u2 = *(const uint4*)(tb + (r2 + chb));
            uint4 u3 = *(const uint4*)(tb + (r3 + chb));
            // bank A takes edges k+0,k+1; bank B takes k+2,k+3 (<=8 adds/bank)
            a0 = __hadd2(a0, *(const __half2*)&u0.x);
            a1 = __hadd2(a1, *(const __half2*)&u0.y);
            a2 = __hadd2(a2, *(const __half2*)&u0.z);
            a3 = __hadd2(a3, *(const __half2*)&u0.w);
            a0 = __hadd2(a0, *(const __half2*)&u1.x);
            a1 = __hadd2(a1, *(const __half2*)&u1.y);
            a2 = __hadd2(a2, *(const __half2*)&u1.z);
            a3 = __hadd2(a3, *(const __half2*)&u1.w);
            b0 = __hadd2(b0, *(const __half2*)&u2.x);
            b1 = __hadd2(b1, *(const __half2*)&u2.y);
            b2 = __hadd2(b2, *(const __half2*)&u2.z);
            b3 = __hadd2(b3, *(const __half2*)&u2.w);
            b0 = __hadd2(b0, *(const __half2*)&u3.x);
            b1 = __hadd2(b1, *(const __half2*)&u3.y);
            b2 = __hadd2(b2, *(const __half2*)&u3.z);
            b3 = __hadd2(b3, *(const __half2*)&u3.w);
        }
        float2 t;
        t = __half22float2(a0); fs0.x += t.x; fs0.y += t.y;
        t = __half22float2(b0); fs0.x += t.x; fs0.y += t.y;
        t = __half22float2(a1); fs1.x += t.x; fs1.y += t.y;
        t = __half22float2(b1); fs1.x += t.x; fs1.y += t.y;
        t = __half22float2(a2); fs2.x += t.x; fs2.y += t.y;
        t = __half22float2(b2); fs2.x += t.x; fs2.y += t.y;
        t = __half22float2(a3); fs3.x += t.x; fs3.y += t.y;
        t = __half22float2(b3); fs3.x += t.x; fs3.y += t.y;
    }
    if (node < N) {
        float gx = __fdividef(fs0.y, fs0.x + 1e-16f);
        float gy = __fdividef(fs1.y, fs1.x + 1e-16f);
        float gz = __fdividef(fs2.y, fs2.x + 1e-16f);
        float gw = __fdividef(fs3.y, fs3.x + 1e-16f);
        uint2 o;
        o.x = (unsigned)__half_as_ushort(__float2half_rn(gx)) |
              ((unsigned)__half_as_ushort(__float2half_rn(gy)) << 16);
        o.y = (unsigned)__half_as_ushort(__float2half_rn(gz)) |
              ((unsigned)__half_as_ushort(__float2half_rn(gw)) << 16);
        *(uint2*)((unsigned char*)agg16 + ((size_t)node << 7) + (l16 << 3)) = o;
    }
}

// ---------------------------------------------------------------------------
// K4 linear via MFMA: out = agg @ W^T + b. One wave per 16 nodes; 4 tiles of
// 16 out-ch; K=64 as two mfma_f32_16x16x32_f16. (Verified correct in R9.)
// ---------------------------------------------------------------------------
__global__ __launch_bounds__(256)
void linear_kernel(const unsigned short* __restrict__ agg16,
                   const unsigned short* __restrict__ Wh,
                   const float* __restrict__ b,
                   float* __restrict__ out, int N, int G) {
    const int tid = threadIdx.x;
    const int wave = tid >> 6;
    const int lane = tid & 63;
    const int l16 = lane & 15;
    const int quad = lane >> 4;
    const int g = blockIdx.x * 4 + wave;
    if (g >= G) return;

    const unsigned char* ab = (const unsigned char*)agg16;
    const unsigned char* wb = (const unsigned char*)Wh;

    half8 a0 = *(const half8*)(ab + (((size_t)(g * 16 + l16)) << 7) + quad * 16);
    half8 a1 = *(const half8*)(ab + (((size_t)(g * 16 + l16)) << 7) + 64 + quad * 16);

    f32x4 acc[4];
    float bias[4];
    #pragma unroll
    for (int t = 0; t < 4; ++t) {
        const unsigned char* wr = wb + (((size_t)(16 * t + l16)) << 7) + quad * 16;
        half8 b0 = *(const half8*)(wr);
        half8 b1 = *(const half8*)(wr + 64);
        acc[t] = (f32x4){0.f, 0.f, 0.f, 0.f};
        acc[t] = __builtin_amdgcn_mfma_f32_16x16x32_f16(a0, b0, acc[t], 0, 0, 0);
        acc[t] = __builtin_amdgcn_mfma_f32_16x16x32_f16(a1, b1, acc[t], 0, 0, 0);
        bias[t] = b[16 * t + l16];
    }
    #pragma unroll
    for (int t = 0; t < 4; ++t) {
        #pragma unroll
        for (int r = 0; r < 4; ++r) {
            int node = g * 16 + quad * 4 + r;
            if (node < N)
                out[((size_t)node << 6) + 16 * t + l16] = acc[t][r] + bias[t];
        }
    }
}

// ---------------------------------------------------------------------------
// launch
// ---------------------------------------------------------------------------
extern "C" void kernel_launch(void* const* d_in, const int* in_sizes, int n_in,
                              void* d_out, int out_size, void* d_ws, size_t ws_size,
                              hipStream_t stream) {
    const float* x    = (const float*)d_in[0];
    const int*   ei   = (const int*)d_in[1];    // [2, E]: row0 = dst, row1 = src
    const float* W    = (const float*)d_in[2];
    const float* b    = (const float*)d_in[3];
    const float* beta = (const float*)d_in[4];
    float* out = (float*)d_out;

    const int N = in_sizes[0] / 64;
    const int E = in_sizes[1] / 2;
    const int* dst = ei;
    const int* src = ei + E;
    const int NB = (N + 255) >> 8;              // 196 coarse buckets
    const int M = N * 64;
    const int G = (N + 15) / 16;                // 16-node groups

    int cap = (E + NB - 1) / NB;
    cap = ((cap + cap / 2 + 256) + 255) & ~255;
    if (cap > 6656) cap = 6656;

    auto align = [](size_t v) { return (v + 255) & ~(size_t)255; };
    size_t off = 0;
    char* ws = (char*)d_ws;
    int2* nse = (int2*)(ws + off);        off += align((size_t)N * 8);
    int* ccur = (int*)(ws + off);         off += align((size_t)NB * 4);
    unsigned* packed = (unsigned*)(ws + off);
    off += align((size_t)NB * cap * 4);
    unsigned short* sorted_src = (unsigned short*)(ws + off);
    off += align((size_t)NB * cap * 2);
    unsigned* tp = (unsigned*)(ws + off);                // (N+1)*64 u32 pairs
    off += align(((size_t)N + 1) * 64 * 4);
    unsigned short* agg16 = (unsigned short*)(ws + off); // G*16*64 fp16
    off += align((size_t)G * 16 * 64 * 2);
    unsigned short* Wh = (unsigned short*)(ws + off);    // 64*64 fp16
    off += align(64 * 64 * 2);

    const int binBlocks  = (E + 2047) / 2048;
    const int prepBlocks = (M + 64 + 8191) / 8192;
    hipMemsetAsync(ccur, 0, (size_t)NB * 4, stream);
    binprep_kernel<<<binBlocks + prepBlocks, 512, 0, stream>>>(
        dst, src, E, cap, x, W, beta, M, ccur, packed, tp, Wh, binBlocks);
    fine_kernel<<<NB, 512, 0, stream>>>(packed, ccur, cap, nse, sorted_src, N);
    gather_kernel<<<G, 256, 0, stream>>>(tp, nse, sorted_src, agg16, N);
    linear_kernel<<<(G + 3) / 4, 256, 0, stream>>>(agg16, Wh, b, out, N, G);
}

// Round 11
// 118.233 us; speedup vs baseline: 1.2967x; 1.1010x over previous
//
#include <hip/hip_runtime.h>
#include <hip/hip_fp16.h>

#define EPS 1e-7f
#define LOG2E 1.4426950408889634f

typedef _Float16 half8 __attribute__((ext_vector_type(8)));
typedef float f32x4 __attribute__((ext_vector_type(4)));

// ---------------------------------------------------------------------------
// K1 (512 thr): blocks [0,binBlocks) bin 2048 edges each into 256-node coarse
// buckets (fixed-capacity windows, LDS-ranked -> contiguous runs). Blocks
// [binBlocks,...) build fp16 table tm[n][c] = (relu(x)+eps)*beta*log2e
// (2B/ch, 128B rows -> 6.4MB table, mostly L2-resident; halves gather bytes
// vs the 4B pair table). Sentinel row N = -1000 (exp2(-1000)=0 exactly ->
// padding contributes nothing). Block binBlocks also converts W to fp16
// row-major for the fused MFMA linear.
// Packed edge entry: (dst&255)<<16 | src  (needs N < 65536).
// ---------------------------------------------------------------------------
__global__ __launch_bounds__(512)
void binprep_kernel(const int* __restrict__ dst,
                    const int* __restrict__ src, int E, int cap,
                    const float* __restrict__ x,
                    const float* __restrict__ W,
                    const float* __restrict__ beta, int M,
                    int* __restrict__ ccur,
                    unsigned* __restrict__ packed,
                    unsigned short* __restrict__ tm,
                    unsigned short* __restrict__ Wh,
                    int binBlocks) {
    if ((int)blockIdx.x < binBlocks) {
        __shared__ int lc[256];
        __shared__ int lbase[256];
        int tid = threadIdx.x;
        if (tid < 256) lc[tid] = 0;
        __syncthreads();
        int e0 = blockIdx.x * 2048;
        int bb[4], rr[4];
        unsigned pk[4];
        #pragma unroll
        for (int i = 0; i < 4; ++i) {
            int e = e0 + i * 512 + tid;
            bb[i] = 0; rr[i] = 0; pk[i] = 0;
            if (e < E) {
                int d = dst[e];
                bb[i] = d >> 8;
                pk[i] = ((unsigned)(d & 255) << 16) | (unsigned)src[e];
                rr[i] = atomicAdd(&lc[bb[i]], 1);
            }
        }
        __syncthreads();
        if (tid < 256) {
            int c = lc[tid];
            if (c) lbase[tid] = tid * cap + atomicAdd(&ccur[tid], c);
        }
        __syncthreads();
        #pragma unroll
        for (int i = 0; i < 4; ++i) {
            int e = e0 + i * 512 + tid;
            if (e < E) packed[lbase[bb[i]] + rr[i]] = pk[i];
        }
    } else {
        int blk = blockIdx.x - binBlocks;
        int tid = threadIdx.x;
        if (blk == 0) {  // convert W (64x64) to fp16 row-major
            #pragma unroll
            for (int j = 0; j < 8; ++j) {
                int i = tid * 8 + j;
                Wh[i] = __half_as_ushort(__float2half_rn(W[i]));
            }
        }
        const float btl = beta[0] * LOG2E;
        const unsigned short sent = __half_as_ushort(__float2half_rn(-1000.f));
        #pragma unroll
        for (int p = 0; p < 4; ++p) {
            int i = blk * 8192 + p * 2048 + tid * 4;
            if (i < M) {
                float4 v = *(const float4*)&x[i];
                ushort4 o;
                o.x = __half_as_ushort(__float2half_rn((fmaxf(v.x, 0.f) + EPS) * btl));
                o.y = __half_as_ushort(__float2half_rn((fmaxf(v.y, 0.f) + EPS) * btl));
                o.z = __half_as_ushort(__float2half_rn((fmaxf(v.z, 0.f) + EPS) * btl));
                o.w = __half_as_ushort(__float2half_rn((fmaxf(v.w, 0.f) + EPS) * btl));
                *(ushort4*)&tm[i] = o;
            } else if (i < M + 64) {
                ushort4 o; o.x = o.y = o.z = o.w = sent;
                *(ushort4*)&tm[i] = o;
            }
        }
    }
}

// ---------------------------------------------------------------------------
// K2 (512 thr): one block per 256-node bucket. Stage packed window in LDS;
// in-LDS hist of dst-low-byte -> 256-wide scan -> per-node (start,end) int2 +
// LDS fine scatter, then coalesced u32-pair write of u16 sorted_src.
// ---------------------------------------------------------------------------
__global__ __launch_bounds__(512)
void fine_kernel(const unsigned* __restrict__ packed,
                 const int* __restrict__ ccur, int cap,
                 int2* __restrict__ nse,
                 unsigned short* __restrict__ sorted_src, int N) {
    __shared__ int lc[256];
    __shared__ int lcur[256];
    __shared__ int wsum[4];
    __shared__ unsigned stage_pk[6656];
    __shared__ unsigned short stage16[6656];
    int tid = threadIdx.x, b = blockIdx.x;
    int rs = b * cap;
    int len = ccur[b];
    if (tid < 256) lc[tid] = 0;
    __syncthreads();
    for (int i = tid; i < len; i += 512) {
        unsigned u = packed[rs + i];
        stage_pk[i] = u;
        atomicAdd(&lc[u >> 16], 1);
    }
    __syncthreads();
    if (tid < 256) {
        int lane = tid & 63, wid = tid >> 6;
        int incl = lc[tid];
        #pragma unroll
        for (int d = 1; d < 64; d <<= 1) {
            int t = __shfl_up(incl, d, 64);
            if (lane >= d) incl += t;
        }
        lcur[tid] = incl;
        if (lane == 63) wsum[wid] = incl;
    }
    __syncthreads();
    if (tid < 256) {
        int wid = tid >> 6;
        int base = 0;
        for (int w = 0; w < wid; ++w) base += wsum[w];
        int v = lc[tid];
        int excl = base + lcur[tid] - v;
        lcur[tid] = excl;
        int node = b * 256 + tid;
        if (node < N) nse[node] = make_int2(rs + excl, rs + excl + v);
    }
    __syncthreads();
    for (int i = tid; i < len; i += 512) {
        unsigned u = stage_pk[i];
        int pos = atomicAdd(&lcur[u >> 16], 1);
        stage16[pos] = (unsigned short)(u & 0xffffu);
    }
    __syncthreads();
    unsigned* dst32 = (unsigned*)&sorted_src[rs];
    int len2 = (len + 1) >> 1;
    for (int i = tid; i < len2; i += 512) {
        unsigned lo = stage16[2 * i];
        unsigned hi = (2 * i + 1 < len) ? (unsigned)stage16[2 * i + 1] : 0u;
        dst32[i] = lo | (hi << 16);
    }
}

// ---------------------------------------------------------------------------
// K3 fused gather+linear (256 thr = 16 nodes = one MFMA tile).
// Gather: quarter-wave per node; 16 lanes x 8B = one full 128B m'-row; lane
// owns 4 channels. s1 = sum 2^m', s2 = sum m'*2^m'; agg = (s2/s1)*ln2/beta.
// Agg (fp16) -> LDS rows (stride 144B: 16B-aligned for ds_read_b128, banks
// 4m%32 -> worst 2-way = free), one sync, then each wave computes its
// 16-out-channel tile with 2x mfma_f32_16x16x32_f16 (R9/R10-verified
// fragment layouts). No agg16 global round-trip, one less dispatch.
// ---------------------------------------------------------------------------
__global__ __launch_bounds__(256)
void gatherlin_kernel(const unsigned short* __restrict__ tm,
                      const int2* __restrict__ nse,
                      const unsigned short* __restrict__ ss,
                      const unsigned short* __restrict__ Wh,
                      const float* __restrict__ bias,
                      const float* __restrict__ beta,
                      float* __restrict__ out, int N) {
    __shared__ short aggS[16 * 72];   // 16 nodes x 64ch fp16, stride 72 halves

    const int tid = threadIdx.x;
    const int wave = tid >> 6;
    const int lane = tid & 63;
    const int quarter = lane >> 4;
    const int l16 = lane & 15;
    const int qbase = quarter << 4;
    const int chb = l16 << 3;            // byte offset in 128B row
    const int sent = N << 7;             // sentinel row byte offset
    const unsigned char* tb = (const unsigned char*)tm;
    const float scale = 0.6931471805599453f / beta[0];   // ln2/beta

    const int g = blockIdx.x;
    const int nl = wave * 4 + quarter;   // node_local 0..15
    const int node = g * 16 + nl;
    int start = 0, cnt = 0;
    if (node < N) { int2 se = nse[node]; start = se.x; cnt = se.y - se.x; }

    float s1x = 0.f, s1y = 0.f, s1z = 0.f, s1w = 0.f;
    float s2x = 0.f, s2y = 0.f, s2z = 0.f, s2w = 0.f;

    for (int chunk = 0; chunk < cnt; chunk += 16) {
        int rem = cnt - chunk;
        if (rem > 16) rem = 16;
        int row = (l16 < rem) ? ((int)ss[start + chunk + l16] << 7) : sent;
        #pragma unroll
        for (int k = 0; k < 16; k += 4) {
            int r0 = __shfl(row, qbase + k + 0, 64);
            int r1 = __shfl(row, qbase + k + 1, 64);
            int r2 = __shfl(row, qbase + k + 2, 64);
            int r3 = __shfl(row, qbase + k + 3, 64);
            uint2 u0 = *(const uint2*)(tb + (r0 + chb));
            uint2 u1 = *(const uint2*)(tb + (r1 + chb));
            uint2 u2 = *(const uint2*)(tb + (r2 + chb));
            uint2 u3 = *(const uint2*)(tb + (r3 + chb));
            #define ACC(u) { \
                float m0 = __half2float(__ushort_as_half((unsigned short)(u.x & 0xffffu))); \
                float m1 = __half2float(__ushort_as_half((unsigned short)(u.x >> 16))); \
                float m2 = __half2float(__ushort_as_half((unsigned short)(u.y & 0xffffu))); \
                float m3 = __half2float(__ushort_as_half((unsigned short)(u.y >> 16))); \
                float e0 = exp2f(m0), e1 = exp2f(m1); \
                float e2 = exp2f(m2), e3 = exp2f(m3); \
                s1x += e0; s2x = fmaf(m0, e0, s2x); \
                s1y += e1; s2y = fmaf(m1, e1, s2y); \
                s1z += e2; s2z = fmaf(m2, e2, s2z); \
                s1w += e3; s2w = fmaf(m3, e3, s2w); }
            ACC(u0); ACC(u1); ACC(u2); ACC(u3);
            #undef ACC
        }
    }

    {   // agg (scaled back by ln2/beta) -> LDS row nl, channels 4*l16..+3
        float gx = __fdividef(s2x, s1x + 1e-16f) * scale;
        float gy = __fdividef(s2y, s1y + 1e-16f) * scale;
        float gz = __fdividef(s2z, s1z + 1e-16f) * scale;
        float gw = __fdividef(s2w, s1w + 1e-16f) * scale;
        uint2 o;
        o.x = (unsigned)__half_as_ushort(__float2half_rn(gx)) |
              ((unsigned)__half_as_ushort(__float2half_rn(gy)) << 16);
        o.y = (unsigned)__half_as_ushort(__float2half_rn(gz)) |
              ((unsigned)__half_as_ushort(__float2half_rn(gw)) << 16);
        *(uint2*)((unsigned char*)aggS + nl * 144 + chb) = o;
    }
    __syncthreads();

    // linear: wave w -> out-channel tile [16w, 16w+16)
    const unsigned char* ab = (const unsigned char*)aggS;
    half8 a0 = *(const half8*)(ab + l16 * 144 + quarter * 16);
    half8 a1 = *(const half8*)(ab + l16 * 144 + 64 + quarter * 16);
    const unsigned char* wr =
        (const unsigned char*)Wh + (((size_t)(wave * 16 + l16)) << 7) + quarter * 16;
    half8 b0 = *(const half8*)(wr);
    half8 b1 = *(const half8*)(wr + 64);
    f32x4 acc = (f32x4){0.f, 0.f, 0.f, 0.f};
    acc = __builtin_amdgcn_mfma_f32_16x16x32_f16(a0, b0, acc, 0, 0, 0);
    acc = __builtin_amdgcn_mfma_f32_16x16x32_f16(a1, b1, acc, 0, 0, 0);
    const float bv = bias[wave * 16 + l16];
    #pragma unroll
    for (int r = 0; r < 4; ++r) {
        int nd = g * 16 + quarter * 4 + r;
        if (nd < N)
            out[((size_t)nd << 6) + wave * 16 + l16] = acc[r] + bv;
    }
}

// ---------------------------------------------------------------------------
// launch
// ---------------------------------------------------------------------------
extern "C" void kernel_launch(void* const* d_in, const int* in_sizes, int n_in,
                              void* d_out, int out_size, void* d_ws, size_t ws_size,
                              hipStream_t stream) {
    const float* x    = (const float*)d_in[0];
    const int*   ei   = (const int*)d_in[1];    // [2, E]: row0 = dst, row1 = src
    const float* W    = (const float*)d_in[2];
    const float* b    = (const float*)d_in[3];
    const float* beta = (const float*)d_in[4];
    float* out = (float*)d_out;

    const int N = in_sizes[0] / 64;
    const int E = in_sizes[1] / 2;
    const int* dst = ei;
    const int* src = ei + E;
    const int NB = (N + 255) >> 8;              // 196 coarse buckets
    const int M = N * 64;
    const int G = (N + 15) / 16;                // 16-node MFMA tiles

    int cap = (E + NB - 1) / NB;
    cap = ((cap + cap / 2 + 256) + 255) & ~255;
    if (cap > 6656) cap = 6656;

    auto align = [](size_t v) { return (v + 255) & ~(size_t)255; };
    size_t off = 0;
    char* ws = (char*)d_ws;
    int2* nse = (int2*)(ws + off);        off += align((size_t)N * 8);
    int* ccur = (int*)(ws + off);         off += align((size_t)NB * 4);
    unsigned* packed = (unsigned*)(ws + off);
    off += align((size_t)NB * cap * 4);
    unsigned short* sorted_src = (unsigned short*)(ws + off);
    off += align((size_t)NB * cap * 2);
    unsigned short* tm = (unsigned short*)(ws + off);   // (N+1)*64 fp16
    off += align(((size_t)N + 1) * 64 * 2);
    unsigned short* Wh = (unsigned short*)(ws + off);   // 64*64 fp16
    off += align(64 * 64 * 2);

    const int binBlocks  = (E + 2047) / 2048;
    const int prepBlocks = (M + 64 + 8191) / 8192;
    hipMemsetAsync(ccur, 0, (size_t)NB * 4, stream);
    binprep_kernel<<<binBlocks + prepBlocks, 512, 0, stream>>>(
        dst, src, E, cap, x, W, beta, M, ccur, packed, tm, Wh, binBlocks);
    fine_kernel<<<NB, 512, 0, stream>>>(packed, ccur, cap, nse, sorted_src, N);
    gatherlin_kernel<<<G, 256, 0, stream>>>(tm, nse, sorted_src, Wh, b, beta,
                                            out, N);
}

// Round 12
// 114.349 us; speedup vs baseline: 1.3408x; 1.0340x over previous
//
#include <hip/hip_runtime.h>
#include <hip/hip_fp16.h>

#define EPS 1e-7f
#define LOG2E 1.4426950408889634f

typedef _Float16 half8 __attribute__((ext_vector_type(8)));
typedef float f32x4 __attribute__((ext_vector_type(4)));

// ---------------------------------------------------------------------------
// K1 (512 thr): blocks [0,binBlocks) bin 2048 edges each into 256-node coarse
// buckets (fixed-capacity windows, LDS-ranked -> contiguous runs). Blocks
// [binBlocks,...) build fp16 table tm[n][c] = (relu(x)+eps)*beta*log2e
// (2B/ch, 128B rows -> 6.4MB table; halves gather bytes vs a 4B pair table).
// Sentinel row N = -1000 (exp2(-1000)=0 exactly -> padding contributes
// nothing). Block binBlocks also converts W to fp16 row-major for the fused
// MFMA linear. Packed edge entry: (dst&255)<<16 | src  (needs N < 65536).
// ---------------------------------------------------------------------------
__global__ __launch_bounds__(512)
void binprep_kernel(const int* __restrict__ dst,
                    const int* __restrict__ src, int E, int cap,
                    const float* __restrict__ x,
                    const float* __restrict__ W,
                    const float* __restrict__ beta, int M,
                    int* __restrict__ ccur,
                    unsigned* __restrict__ packed,
                    unsigned short* __restrict__ tm,
                    unsigned short* __restrict__ Wh,
                    int binBlocks) {
    if ((int)blockIdx.x < binBlocks) {
        __shared__ int lc[256];
        __shared__ int lbase[256];
        int tid = threadIdx.x;
        if (tid < 256) lc[tid] = 0;
        __syncthreads();
        int e0 = blockIdx.x * 2048;
        int bb[4], rr[4];
        unsigned pk[4];
        #pragma unroll
        for (int i = 0; i < 4; ++i) {
            int e = e0 + i * 512 + tid;
            bb[i] = 0; rr[i] = 0; pk[i] = 0;
            if (e < E) {
                int d = dst[e];
                bb[i] = d >> 8;
                pk[i] = ((unsigned)(d & 255) << 16) | (unsigned)src[e];
                rr[i] = atomicAdd(&lc[bb[i]], 1);
            }
        }
        __syncthreads();
        if (tid < 256) {
            int c = lc[tid];
            if (c) lbase[tid] = tid * cap + atomicAdd(&ccur[tid], c);
        }
        __syncthreads();
        #pragma unroll
        for (int i = 0; i < 4; ++i) {
            int e = e0 + i * 512 + tid;
            if (e < E) packed[lbase[bb[i]] + rr[i]] = pk[i];
        }
    } else {
        int blk = blockIdx.x - binBlocks;
        int tid = threadIdx.x;
        if (blk == 0) {  // convert W (64x64) to fp16 row-major
            #pragma unroll
            for (int j = 0; j < 8; ++j) {
                int i = tid * 8 + j;
                Wh[i] = __half_as_ushort(__float2half_rn(W[i]));
            }
        }
        const float btl = beta[0] * LOG2E;
        const unsigned short sent = __half_as_ushort(__float2half_rn(-1000.f));
        #pragma unroll
        for (int p = 0; p < 4; ++p) {
            int i = blk * 8192 + p * 2048 + tid * 4;
            if (i < M) {
                float4 v = *(const float4*)&x[i];
                ushort4 o;
                o.x = __half_as_ushort(__float2half_rn((fmaxf(v.x, 0.f) + EPS) * btl));
                o.y = __half_as_ushort(__float2half_rn((fmaxf(v.y, 0.f) + EPS) * btl));
                o.z = __half_as_ushort(__float2half_rn((fmaxf(v.z, 0.f) + EPS) * btl));
                o.w = __half_as_ushort(__float2half_rn((fmaxf(v.w, 0.f) + EPS) * btl));
                *(ushort4*)&tm[i] = o;
            } else if (i < M + 64) {
                ushort4 o; o.x = o.y = o.z = o.w = sent;
                *(ushort4*)&tm[i] = o;
            }
        }
    }
}

// ---------------------------------------------------------------------------
// K2 (512 thr): one block per 256-node bucket. Stage packed window in LDS;
// in-LDS hist of dst-low-byte -> 256-wide scan -> per-node (start,end) int2 +
// LDS fine scatter, then coalesced u32-pair write of u16 sorted_src.
// ---------------------------------------------------------------------------
__global__ __launch_bounds__(512)
void fine_kernel(const unsigned* __restrict__ packed,
                 const int* __restrict__ ccur, int cap,
                 int2* __restrict__ nse,
                 unsigned short* __restrict__ sorted_src, int N) {
    __shared__ int lc[256];
    __shared__ int lcur[256];
    __shared__ int wsum[4];
    __shared__ unsigned stage_pk[6656];
    __shared__ unsigned short stage16[6656];
    int tid = threadIdx.x, b = blockIdx.x;
    int rs = b * cap;
    int len = ccur[b];
    if (tid < 256) lc[tid] = 0;
    __syncthreads();
    for (int i = tid; i < len; i += 512) {
        unsigned u = packed[rs + i];
        stage_pk[i] = u;
        atomicAdd(&lc[u >> 16], 1);
    }
    __syncthreads();
    if (tid < 256) {
        int lane = tid & 63, wid = tid >> 6;
        int incl = lc[tid];
        #pragma unroll
        for (int d = 1; d < 64; d <<= 1) {
            int t = __shfl_up(incl, d, 64);
            if (lane >= d) incl += t;
        }
        lcur[tid] = incl;
        if (lane == 63) wsum[wid] = incl;
    }
    __syncthreads();
    if (tid < 256) {
        int wid = tid >> 6;
        int base = 0;
        for (int w = 0; w < wid; ++w) base += wsum[w];
        int v = lc[tid];
        int excl = base + lcur[tid] - v;
        lcur[tid] = excl;
        int node = b * 256 + tid;
        if (node < N) nse[node] = make_int2(rs + excl, rs + excl + v);
    }
    __syncthreads();
    for (int i = tid; i < len; i += 512) {
        unsigned u = stage_pk[i];
        int pos = atomicAdd(&lcur[u >> 16], 1);
        stage16[pos] = (unsigned short)(u & 0xffffu);
    }
    __syncthreads();
    unsigned* dst32 = (unsigned*)&sorted_src[rs];
    int len2 = (len + 1) >> 1;
    for (int i = tid; i < len2; i += 512) {
        unsigned lo = stage16[2 * i];
        unsigned hi = (2 * i + 1 < len) ? (unsigned)stage16[2 * i + 1] : 0u;
        dst32[i] = lo | (hi << 16);
    }
}

// ---------------------------------------------------------------------------
// K3 fused gather+linear (256 thr = 16 nodes = one MFMA tile).
// Gather: quarter-wave per node; 16 lanes x 8B = one full 128B m'-row; lane
// owns 4 channels. Inner k-loop has a RUNTIME bound (k < rem): with
// Poisson(16) degrees the static 16-iteration version wasted ~33% of all
// loads/ACCs on sentinel padding; runtime bound cuts that to <=3 slots/node.
// s1 = sum 2^m', s2 = sum m'*2^m'; agg = (s2/s1)*ln2/beta. Agg (fp16) ->
// LDS rows (stride 144B: 16B-aligned for ds_read_b128, banks 4m%32 ->
// worst 2-way = free), one sync, then each wave computes its 16-out-channel
// tile with 2x mfma_f32_16x16x32_f16 (verified fragment layouts).
// ---------------------------------------------------------------------------
__global__ __launch_bounds__(256)
void gatherlin_kernel(const unsigned short* __restrict__ tm,
                      const int2* __restrict__ nse,
                      const unsigned short* __restrict__ ss,
                      const unsigned short* __restrict__ Wh,
                      const float* __restrict__ bias,
                      const float* __restrict__ beta,
                      float* __restrict__ out, int N) {
    __shared__ short aggS[16 * 72];   // 16 nodes x 64ch fp16, stride 72 halves

    const int tid = threadIdx.x;
    const int wave = tid >> 6;
    const int lane = tid & 63;
    const int quarter = lane >> 4;
    const int l16 = lane & 15;
    const int qbase = quarter << 4;
    const int chb = l16 << 3;            // byte offset in 128B row
    const int sent = N << 7;             // sentinel row byte offset
    const unsigned char* tb = (const unsigned char*)tm;
    const float scale = 0.6931471805599453f / beta[0];   // ln2/beta

    const int g = blockIdx.x;
    const int nl = wave * 4 + quarter;   // node_local 0..15
    const int node = g * 16 + nl;
    int start = 0, cnt = 0;
    if (node < N) { int2 se = nse[node]; start = se.x; cnt = se.y - se.x; }

    float s1x = 0.f, s1y = 0.f, s1z = 0.f, s1w = 0.f;
    float s2x = 0.f, s2y = 0.f, s2z = 0.f, s2w = 0.f;

    for (int chunk = 0; chunk < cnt; chunk += 16) {
        int rem = cnt - chunk;
        if (rem > 16) rem = 16;
        int row = (l16 < rem) ? ((int)ss[start + chunk + l16] << 7) : sent;
        // runtime trip count: only ceil(rem/4) groups issue loads/ACCs.
        // Lanes >= rem hold the sentinel row (exp2(-1000) == 0 -> exact).
        #pragma unroll 1
        for (int k = 0; k < rem; k += 4) {
            int r0 = __shfl(row, qbase + k + 0, 64);
            int r1 = __shfl(row, qbase + k + 1, 64);
            int r2 = __shfl(row, qbase + k + 2, 64);
            int r3 = __shfl(row, qbase + k + 3, 64);
            uint2 u0 = *(const uint2*)(tb + (r0 + chb));
            uint2 u1 = *(const uint2*)(tb + (r1 + chb));
            uint2 u2 = *(const uint2*)(tb + (r2 + chb));
            uint2 u3 = *(const uint2*)(tb + (r3 + chb));
            #define ACC(u) { \
                float m0 = __half2float(__ushort_as_half((unsigned short)(u.x & 0xffffu))); \
                float m1 = __half2float(__ushort_as_half((unsigned short)(u.x >> 16))); \
                float m2 = __half2float(__ushort_as_half((unsigned short)(u.y & 0xffffu))); \
                float m3 = __half2float(__ushort_as_half((unsigned short)(u.y >> 16))); \
                float e0 = exp2f(m0), e1 = exp2f(m1); \
                float e2 = exp2f(m2), e3 = exp2f(m3); \
                s1x += e0; s2x = fmaf(m0, e0, s2x); \
                s1y += e1; s2y = fmaf(m1, e1, s2y); \
                s1z += e2; s2z = fmaf(m2, e2, s2z); \
                s1w += e3; s2w = fmaf(m3, e3, s2w); }
            ACC(u0); ACC(u1); ACC(u2); ACC(u3);
            #undef ACC
        }
    }

    {   // agg (scaled back by ln2/beta) -> LDS row nl, channels 4*l16..+3
        float gx = __fdividef(s2x, s1x + 1e-16f) * scale;
        float gy = __fdividef(s2y, s1y + 1e-16f) * scale;
        float gz = __fdividef(s2z, s1z + 1e-16f) * scale;
        float gw = __fdividef(s2w, s1w + 1e-16f) * scale;
        uint2 o;
        o.x = (unsigned)__half_as_ushort(__float2half_rn(gx)) |
              ((unsigned)__half_as_ushort(__float2half_rn(gy)) << 16);
        o.y = (unsigned)__half_as_ushort(__float2half_rn(gz)) |
              ((unsigned)__half_as_ushort(__float2half_rn(gw)) << 16);
        *(uint2*)((unsigned char*)aggS + nl * 144 + chb) = o;
    }
    __syncthreads();

    // linear: wave w -> out-channel tile [16w, 16w+16)
    const unsigned char* ab = (const unsigned char*)aggS;
    half8 a0 = *(const half8*)(ab + l16 * 144 + quarter * 16);
    half8 a1 = *(const half8*)(ab + l16 * 144 + 64 + quarter * 16);
    const unsigned char* wr =
        (const unsigned char*)Wh + (((size_t)(wave * 16 + l16)) << 7) + quarter * 16;
    half8 b0 = *(const half8*)(wr);
    half8 b1 = *(const half8*)(wr + 64);
    f32x4 acc = (f32x4){0.f, 0.f, 0.f, 0.f};
    acc = __builtin_amdgcn_mfma_f32_16x16x32_f16(a0, b0, acc, 0, 0, 0);
    acc = __builtin_amdgcn_mfma_f32_16x16x32_f16(a1, b1, acc, 0, 0, 0);
    const float bv = bias[wave * 16 + l16];
    #pragma unroll
    for (int r = 0; r < 4; ++r) {
        int nd = g * 16 + quarter * 4 + r;
        if (nd < N)
            out[((size_t)nd << 6) + wave * 16 + l16] = acc[r] + bv;
    }
}

// ---------------------------------------------------------------------------
// launch
// ---------------------------------------------------------------------------
extern "C" void kernel_launch(void* const* d_in, const int* in_sizes, int n_in,
                              void* d_out, int out_size, void* d_ws, size_t ws_size,
                              hipStream_t stream) {
    const float* x    = (const float*)d_in[0];
    const int*   ei   = (const int*)d_in[1];    // [2, E]: row0 = dst, row1 = src
    const float* W    = (const float*)d_in[2];
    const float* b    = (const float*)d_in[3];
    const float* beta = (const float*)d_in[4];
    float* out = (float*)d_out;

    const int N = in_sizes[0] / 64;
    const int E = in_sizes[1] / 2;
    const int* dst = ei;
    const int* src = ei + E;
    const int NB = (N + 255) >> 8;              // 196 coarse buckets
    const int M = N * 64;
    const int G = (N + 15) / 16;                // 16-node MFMA tiles

    int cap = (E + NB - 1) / NB;
    cap = ((cap + cap / 2 + 256) + 255) & ~255;
    if (cap > 6656) cap = 6656;

    auto align = [](size_t v) { return (v + 255) & ~(size_t)255; };
    size_t off = 0;
    char* ws = (char*)d_ws;
    int2* nse = (int2*)(ws + off);        off += align((size_t)N * 8);
    int* ccur = (int*)(ws + off);         off += align((size_t)NB * 4);
    unsigned* packed = (unsigned*)(ws + off);
    off += align((size_t)NB * cap * 4);
    unsigned short* sorted_src = (unsigned short*)(ws + off);
    off += align((size_t)NB * cap * 2);
    unsigned short* tm = (unsigned short*)(ws + off);   // (N+1)*64 fp16
    off += align(((size_t)N + 1) * 64 * 2);
    unsigned short* Wh = (unsigned short*)(ws + off);   // 64*64 fp16
    off += align(64 * 64 * 2);

    const int binBlocks  = (E + 2047) / 2048;
    const int prepBlocks = (M + 64 + 8191) / 8192;
    hipMemsetAsync(ccur, 0, (size_t)NB * 4, stream);
    binprep_kernel<<<binBlocks + prepBlocks, 512, 0, stream>>>(
        dst, src, E, cap, x, W, beta, M, ccur, packed, tm, Wh, binBlocks);
    fine_kernel<<<NB, 512, 0, stream>>>(packed, ccur, cap, nse, sorted_src, N);
    gatherlin_kernel<<<G, 256, 0, stream>>>(tm, nse, sorted_src, Wh, b, beta,
                                            out, N);
}

// Round 13
// 113.544 us; speedup vs baseline: 1.3503x; 1.0071x over previous
//
#include <hip/hip_runtime.h>
#include <hip/hip_fp16.h>

#define EPS 1e-7f
#define LOG2E 1.4426950408889634f
#define CAP 384          // per-bucket edge window: mean 256 + 8 sigma
#define NBMAX 3136       // max 16-node buckets

typedef _Float16 half8 __attribute__((ext_vector_type(8)));
typedef float f32x4 __attribute__((ext_vector_type(4)));

// ---------------------------------------------------------------------------
// K1 (512 thr): blocks [0,binBlocks) bin 8192 edges each into 16-node buckets
// (fixed-capacity windows, LDS-ranked). Blocks [binBlocks,...) build fp16
// table tm[n][c] = (relu(x)+eps)*beta*log2e (2B/ch, 128B rows); sentinel row
// N = -1000 (exp2 -> 0 exactly). Block binBlocks also converts W to fp16.
// Packed edge entry: (dst&15)<<16 | src  (needs N < 65536).
// ---------------------------------------------------------------------------
__global__ __launch_bounds__(512)
void binprep_kernel(const int* __restrict__ dst,
                    const int* __restrict__ src, int E, int NB,
                    const float* __restrict__ x,
                    const float* __restrict__ W,
                    const float* __restrict__ beta, int M,
                    int* __restrict__ ccur,
                    unsigned* __restrict__ packed,
                    unsigned short* __restrict__ tm,
                    unsigned short* __restrict__ Wh,
                    int binBlocks) {
    if ((int)blockIdx.x < binBlocks) {
        __shared__ int lc[NBMAX];
        __shared__ int lbase[NBMAX];
        int tid = threadIdx.x;
        for (int i = tid; i < NB; i += 512) lc[i] = 0;
        __syncthreads();
        int e0 = blockIdx.x * 8192;
        int bb[16], rr[16];
        unsigned pk[16];
        #pragma unroll
        for (int i = 0; i < 16; ++i) {
            int e = e0 + i * 512 + tid;
            bb[i] = 0; rr[i] = 0; pk[i] = 0;
            if (e < E) {
                int d = dst[e];
                bb[i] = d >> 4;
                pk[i] = ((unsigned)(d & 15) << 16) | (unsigned)src[e];
                rr[i] = atomicAdd(&lc[bb[i]], 1);
            }
        }
        __syncthreads();
        for (int i = tid; i < NB; i += 512) {
            int c = lc[i];
            if (c) lbase[i] = i * CAP + atomicAdd(&ccur[i], c);
        }
        __syncthreads();
        #pragma unroll
        for (int i = 0; i < 16; ++i) {
            int e = e0 + i * 512 + tid;
            if (e < E) {
                int pos = lbase[bb[i]] + rr[i];
                if (pos < (bb[i] + 1) * CAP)   // overflow guard (8-sigma cap)
                    packed[pos] = pk[i];
            }
        }
    } else {
        int blk = blockIdx.x - binBlocks;
        int tid = threadIdx.x;
        if (blk == 0) {  // convert W (64x64) to fp16 row-major
            #pragma unroll
            for (int j = 0; j < 8; ++j) {
                int i = tid * 8 + j;
                Wh[i] = __half_as_ushort(__float2half_rn(W[i]));
            }
        }
        const float btl = beta[0] * LOG2E;
        const unsigned short sent = __half_as_ushort(__float2half_rn(-1000.f));
        #pragma unroll
        for (int p = 0; p < 4; ++p) {
            int i = blk * 8192 + p * 2048 + tid * 4;
            if (i < M) {
                float4 v = *(const float4*)&x[i];
                ushort4 o;
                o.x = __half_as_ushort(__float2half_rn((fmaxf(v.x, 0.f) + EPS) * btl));
                o.y = __half_as_ushort(__float2half_rn((fmaxf(v.y, 0.f) + EPS) * btl));
                o.z = __half_as_ushort(__float2half_rn((fmaxf(v.z, 0.f) + EPS) * btl));
                o.w = __half_as_ushort(__float2half_rn((fmaxf(v.w, 0.f) + EPS) * btl));
                *(ushort4*)&tm[i] = o;
            } else if (i < M + 64) {
                ushort4 o; o.x = o.y = o.z = o.w = sent;
                *(ushort4*)&tm[i] = o;
            }
        }
    }
}

// ---------------------------------------------------------------------------
// K2 fused sort+gather+linear (256 thr = one 16-node bucket = one MFMA tile).
// In-LDS: 16-counter hist -> 16-wide scan (lists padded to x4 with sentinel
// id N; stage16 pre-filled with N) -> scatter. Gather: quarter-wave per
// node, per 4 edges one uniform ds_read_b64 of ids (LDS broadcast, no shfl)
// -> 4 independent dwordx2 row loads; s1 = sum 2^m', s2 = sum m'*2^m';
// agg = (s2/s1)*ln2/beta. Agg (fp16) -> LDS rows (stride 144B), one sync,
// MFMA 16x16x32_f16 x2 per wave (verified layouts), bias, store.
// ---------------------------------------------------------------------------
__global__ __launch_bounds__(256)
void gatherlin_kernel(const unsigned* __restrict__ packed,
                      const int* __restrict__ ccur,
                      const unsigned short* __restrict__ tm,
                      const unsigned short* __restrict__ Wh,
                      const float* __restrict__ bias,
                      const float* __restrict__ beta,
                      float* __restrict__ out, int N) {
    __shared__ unsigned stage_pk[CAP];
    __shared__ unsigned short stage16[CAP + 64];
    __shared__ short aggS[16 * 72];
    __shared__ int lc[16], nstart[16], lcur[16];

    const int tid = threadIdx.x;
    const int b = blockIdx.x;
    const unsigned short sentid = (unsigned short)N;

    int len = ccur[b];
    if (len > CAP) len = CAP;
    const int rs = b * CAP;

    if (tid < 16) lc[tid] = 0;
    for (int i = tid; i < CAP + 64; i += 256) stage16[i] = sentid;
    __syncthreads();

    for (int i = tid; i < len; i += 256) {
        unsigned u = packed[rs + i];
        stage_pk[i] = u;
        atomicAdd(&lc[u >> 16], 1);
    }
    __syncthreads();

    if (tid < 16) {   // 16-wide scan of 4-rounded counts (wave 0)
        int c4 = (lc[tid] + 3) & ~3;
        int incl = c4;
        #pragma unroll
        for (int d = 1; d < 16; d <<= 1) {
            int t = __shfl_up(incl, d, 64);
            if (tid >= d) incl += t;
        }
        nstart[tid] = incl - c4;
        lcur[tid] = incl - c4;
    }
    __syncthreads();

    for (int i = tid; i < len; i += 256) {
        unsigned u = stage_pk[i];
        int pos = atomicAdd(&lcur[u >> 16], 1);
        stage16[pos] = (unsigned short)(u & 0xffffu);
    }
    __syncthreads();

    const int wave = tid >> 6;
    const int lane = tid & 63;
    const int quarter = lane >> 4;
    const int l16 = lane & 15;
    const int chb = l16 << 3;            // byte offset in 128B row
    const unsigned char* tb = (const unsigned char*)tm;
    const float scale = 0.6931471805599453f / beta[0];   // ln2/beta

    const int nl = wave * 4 + quarter;   // node_local 0..15
    const int node = b * 16 + nl;
    const int start = nstart[nl];
    const int cnt = lc[nl];

    float s1x = 0.f, s1y = 0.f, s1z = 0.f, s1w = 0.f;
    float s2x = 0.f, s2y = 0.f, s2z = 0.f, s2w = 0.f;

    #pragma unroll 1
    for (int k = 0; k < cnt; k += 4) {
        // 4 edge ids via one 8B LDS broadcast read (start is 4-aligned)
        uint2 e4 = *(const uint2*)&stage16[start + k];
        int r0 = (int)(e4.x & 0xffffu) << 7;
        int r1 = (int)(e4.x >> 16) << 7;
        int r2 = (int)(e4.y & 0xffffu) << 7;
        int r3 = (int)(e4.y >> 16) << 7;
        uint2 u0 = *(const uint2*)(tb + (r0 + chb));
        uint2 u1 = *(const uint2*)(tb + (r1 + chb));
        uint2 u2 = *(const uint2*)(tb + (r2 + chb));
        uint2 u3 = *(const uint2*)(tb + (r3 + chb));
        #define ACC(u) { \
            float m0 = __half2float(__ushort_as_half((unsigned short)(u.x & 0xffffu))); \
            float m1 = __half2float(__ushort_as_half((unsigned short)(u.x >> 16))); \
            float m2 = __half2float(__ushort_as_half((unsigned short)(u.y & 0xffffu))); \
            float m3 = __half2float(__ushort_as_half((unsigned short)(u.y >> 16))); \
            float e0 = exp2f(m0), e1 = exp2f(m1); \
            float e2 = exp2f(m2), e3 = exp2f(m3); \
            s1x += e0; s2x = fmaf(m0, e0, s2x); \
            s1y += e1; s2y = fmaf(m1, e1, s2y); \
            s1z += e2; s2z = fmaf(m2, e2, s2z); \
            s1w += e3; s2w = fmaf(m3, e3, s2w); }
        ACC(u0); ACC(u1); ACC(u2); ACC(u3);
        #undef ACC
    }

    {   // agg (scaled by ln2/beta) -> LDS row nl, channels 4*l16..+3
        float gx = __fdividef(s2x, s1x + 1e-16f) * scale;
        float gy = __fdividef(s2y, s1y + 1e-16f) * scale;
        float gz = __fdividef(s2z, s1z + 1e-16f) * scale;
        float gw = __fdividef(s2w, s1w + 1e-16f) * scale;
        uint2 o;
        o.x = (unsigned)__half_as_ushort(__float2half_rn(gx)) |
              ((unsigned)__half_as_ushort(__float2half_rn(gy)) << 16);
        o.y = (unsigned)__half_as_ushort(__float2half_rn(gz)) |
              ((unsigned)__half_as_ushort(__float2half_rn(gw)) << 16);
        *(uint2*)((unsigned char*)aggS + nl * 144 + chb) = o;
    }
    __syncthreads();

    // linear: wave w -> out-channel tile [16w, 16w+16)
    const unsigned char* ab = (const unsigned char*)aggS;
    half8 a0 = *(const half8*)(ab + l16 * 144 + quarter * 16);
    half8 a1 = *(const half8*)(ab + l16 * 144 + 64 + quarter * 16);
    const unsigned char* wr =
        (const unsigned char*)Wh + (((size_t)(wave * 16 + l16)) << 7) + quarter * 16;
    half8 b0 = *(const half8*)(wr);
    half8 b1 = *(const half8*)(wr + 64);
    f32x4 acc = (f32x4){0.f, 0.f, 0.f, 0.f};
    acc = __builtin_amdgcn_mfma_f32_16x16x32_f16(a0, b0, acc, 0, 0, 0);
    acc = __builtin_amdgcn_mfma_f32_16x16x32_f16(a1, b1, acc, 0, 0, 0);
    const float bv = bias[wave * 16 + l16];
    #pragma unroll
    for (int r = 0; r < 4; ++r) {
        int nd = b * 16 + quarter * 4 + r;
        if (nd < N)
            out[((size_t)nd << 6) + wave * 16 + l16] = acc[r] + bv;
    }
}

// ---------------------------------------------------------------------------
// launch
// ---------------------------------------------------------------------------
extern "C" void kernel_launch(void* const* d_in, const int* in_sizes, int n_in,
                              void* d_out, int out_size, void* d_ws, size_t ws_size,
                              hipStream_t stream) {
    const float* x    = (const float*)d_in[0];
    const int*   ei   = (const int*)d_in[1];    // [2, E]: row0 = dst, row1 = src
    const float* W    = (const float*)d_in[2];
    const float* b    = (const float*)d_in[3];
    const float* beta = (const float*)d_in[4];
    float* out = (float*)d_out;

    const int N = in_sizes[0] / 64;
    const int E = in_sizes[1] / 2;
    const int* dst = ei;
    const int* src = ei + E;
    const int NB = (N + 15) >> 4;               // 3125 buckets of 16 nodes
    const int M = N * 64;

    auto align = [](size_t v) { return (v + 255) & ~(size_t)255; };
    size_t off = 0;
    char* ws = (char*)d_ws;
    int* ccur = (int*)(ws + off);         off += align((size_t)NB * 4);
    unsigned* packed = (unsigned*)(ws + off);
    off += align((size_t)NB * CAP * 4);
    unsigned short* tm = (unsigned short*)(ws + off);   // (N+1)*64 fp16
    off += align(((size_t)N + 1) * 64 * 2);
    unsigned short* Wh = (unsigned short*)(ws + off);   // 64*64 fp16
    off += align(64 * 64 * 2);

    const int binBlocks  = (E + 8191) / 8192;           // 98
    const int prepBlocks = (M + 64 + 8191) / 8192;      // 391
    hipMemsetAsync(ccur, 0, (size_t)NB * 4, stream);
    binprep_kernel<<<binBlocks + prepBlocks, 512, 0, stream>>>(
        dst, src, E, NB, x, W, beta, M, ccur, packed, tm, Wh, binBlocks);
    gatherlin_kernel<<<NB, 256, 0, stream>>>(packed, ccur, tm, Wh, b, beta,
                                             out, N);
}